// Round 14
// baseline (195.709 us; speedup 1.0000x reference)
//
#include <hip/hip_runtime.h>
#include <hip/hip_bf16.h>
#include <math.h>

#define NB 128   // batch
#define NR 36    // regions
#define NW 32    // words
#define ND 256   // feature dim

#define MARGINf 0.05f
#define TEMPf   14.0f
#define LAMf    9.0f
#define EPSf    1e-8f
#define LOG2Ef  1.4426950408889634f

typedef _Float16 f16x8 __attribute__((ext_vector_type(8)));
typedef _Float16 f16x4 __attribute__((ext_vector_type(4)));
typedef float    f32x4 __attribute__((ext_vector_type(4)));

// ================= workspace layout (float offsets) =================
// All GEMM operands stored in MFMA-fragment order ("swizzled"):
//   fragment f, lane l, elem j  ->  base + f*512 + l*8 + j   (halves)
// so a wave's f16x8 fragment load = 64 lanes x 16B contiguous = 1KB burst.
#define WS_SCORES 0
#define WS_N1     16384
#define WS_GW     20480                   // f16[128][6*512]   (rt*2+ks frags)
#define GW_H      3072
#define WS_IMW    217088                  // f16[128][24*512]  (mt*8+ks frags)
#define IMW_H     12288
#define WS_SHW    1003520                 // f16[128][16*512]  (nt*8+ks frags)
#define SHW_H     8192

// =====================================================================
// prep4: build swizzled f16 operands (imw, shw word-masked, Gw) + n1
// =====================================================================
__global__ __launch_bounds__(256) void prep4_kernel(
    const float* __restrict__ im, const float* __restrict__ s,
    const int* __restrict__ s_l, float* __restrict__ ws)
{
    const int b = blockIdx.x;
    const int t = threadIdx.x;
    __shared__ float s_imf[NR * 260];
    __shared__ _Float16 s_G[48 * 72];

    const float4* im4 = (const float4*)(im + (size_t)b * NR * ND);
    for (int i = t; i < NR * 64; i += 256) {
        int r = i >> 6, c4 = i & 63;
        *(float4*)&s_imf[r * 260 + 4 * c4] = im4[i];
    }
    // zero G LDS (1728 u32)
    for (int i = t; i < 1728; i += 256) ((unsigned int*)s_G)[i] = 0u;
    __syncthreads();

    // Gram f16 into LDS [48][72], fill 36x36
    for (int i = t; i < NR * NR; i += 256) {
        int r = i / NR, rp = i - r * NR;
        const float4* a  = (const float4*)&s_imf[r * 260];
        const float4* bb = (const float4*)&s_imf[rp * 260];
        float acc = 0.f;
        for (int k = 0; k < 64; ++k) {
            float4 x = a[k], y = bb[k];
            acc += x.x * y.x + x.y * y.y + x.z * y.z + x.w * y.w;
        }
        s_G[r * 72 + rp] = (_Float16)acc;
    }
    __syncthreads();

    // Gw swizzled: 6 fragments (rt*2+ks) x 64 lanes
    _Float16* Gw = (_Float16*)(ws + WS_GW) + (size_t)b * GW_H;
    for (int i = t; i < 6 * 64; i += 256) {
        const int f = i >> 6, l = i & 63;
        const int rt = f >> 1, ks = f & 1;
        const int lm = l & 15, kg = l >> 4;
        f16x8 h = *(const f16x8*)&s_G[(rt * 16 + lm) * 72 + ks * 32 + kg * 8];
        *(f16x8*)((_Float16*)Gw + f * 512 + l * 8) = h;
    }

    // imw swizzled: 24 fragments (mt*8+ks) x 64 lanes, rows >=36 zero
    _Float16* imw = (_Float16*)(ws + WS_IMW) + (size_t)b * IMW_H;
    for (int i = t; i < 24 * 64; i += 256) {
        const int f = i >> 6, l = i & 63;
        const int mt = f >> 3, ks = f & 7;
        const int lm = l & 15, kg = l >> 4;
        const int r = mt * 16 + lm;
        f16x8 h;
        if (r < NR) {
            const int k0 = ks * 32 + kg * 8;
            const float4 a  = *(const float4*)&s_imf[r * 260 + k0];
            const float4 bb = *(const float4*)&s_imf[r * 260 + k0 + 4];
            h[0] = (_Float16)a.x;  h[1] = (_Float16)a.y;
            h[2] = (_Float16)a.z;  h[3] = (_Float16)a.w;
            h[4] = (_Float16)bb.x; h[5] = (_Float16)bb.y;
            h[6] = (_Float16)bb.z; h[7] = (_Float16)bb.w;
        } else {
#pragma unroll
            for (int k = 0; k < 8; ++k) h[k] = (_Float16)0.f;
        }
        *(f16x8*)(imw + f * 512 + l * 8) = h;
    }

    // shw swizzled: 16 fragments (nt*8+ks) x 64 lanes, word-masked
    const int sl = s_l[b];
    _Float16* shw = (_Float16*)(ws + WS_SHW) + (size_t)b * SHW_H;
    const float4* s4 = (const float4*)(s + (size_t)b * NW * ND);
    for (int i = t; i < 16 * 64; i += 256) {
        const int f = i >> 6, l = i & 63;
        const int nt = f >> 3, ks = f & 7;
        const int lm = l & 15, kg = l >> 4;
        const int w = nt * 16 + lm;
        f16x8 h;
        if (w < sl) {
            const int k0 = ks * 32 + kg * 8;     // multiple of 8 floats
            const float4 a  = s4[w * 64 + (k0 >> 2)];
            const float4 bb = s4[w * 64 + (k0 >> 2) + 1];
            h[0] = (_Float16)a.x;  h[1] = (_Float16)a.y;
            h[2] = (_Float16)a.z;  h[3] = (_Float16)a.w;
            h[4] = (_Float16)bb.x; h[5] = (_Float16)bb.y;
            h[6] = (_Float16)bb.z; h[7] = (_Float16)bb.w;
        } else {
#pragma unroll
            for (int k = 0; k < 8; ++k) h[k] = (_Float16)0.f;
        }
        *(f16x8*)(shw + f * 512 + l * 8) = h;
    }

    // n1[b][w]
    {
        const int w = t >> 3, g = t & 7;
        float acc = 0.f;
        for (int j = 0; j < 8; ++j) {
            float4 v = s4[w * 64 + g * 8 + j];
            acc += v.x * v.x + v.y * v.y + v.z * v.z + v.w * v.w;
        }
        acc += __shfl_down(acc, 4, 8);
        acc += __shfl_down(acc, 2, 8);
        acc += __shfl_down(acc, 1, 8);
        if (g == 0) ws[WS_N1 + b * NW + w] = sqrtf(acc);
    }
}

// =====================================================================
// wavefused5: ONE WAVE per (image b, caption c), ZERO barriers.
// No er[] register copy of E -> ~72-80 regs/wave -> 6 waves/SIMD target.
// n2 dot reads E back from LDS (C-layout-aligned f16x4).
// grid (32, 128), block 256 = 4 independent waves. LDS ~18.5 KB.
// =====================================================================
__global__ __launch_bounds__(256, 6) void wavefused5_kernel(
    const int* __restrict__ s_l, const float* __restrict__ im_mask,
    float* __restrict__ ws)
{
    const int t = threadIdx.x;
    const int wv = t >> 6, lane = t & 63;
    const int lm = lane & 15, kg = lane >> 4;
    const int b = blockIdx.y;
    const int c = blockIdx.x * 4 + wv;

    __shared__ _Float16 sE[4][32 * 72];   // per-wave E tile [w][k], 4.6 KB each

    const _Float16* aB = (const _Float16*)(ws + WS_IMW) + (size_t)b * IMW_H + lane * 8;
    const _Float16* bB = (const _Float16*)(ws + WS_SHW) + (size_t)c * SHW_H + lane * 8;
    const _Float16* gB = (const _Float16*)(ws + WS_GW) + (size_t)b * GW_H + lane * 8;

    // early small loads (L1/L2-resident, broadcast-friendly)
    float n1v[2];
#pragma unroll
    for (int nt = 0; nt < 2; ++nt)
        n1v[nt] = ws[WS_N1 + c * NW + nt * 16 + lm];
    float mr[12];
#pragma unroll
    for (int mt = 0; mt < 3; ++mt)
#pragma unroll
        for (int v = 0; v < 4; ++v) {
            const int r = mt * 16 + kg * 4 + v;
            mr[mt * 4 + v] = (r < NR) ? im_mask[b * NR + r] : 0.f;
        }
    const int sl = s_l[c];

    // accumulator array, aliased:
    //   phase 1: accv[mt*2+nt] = A0 raw tile
    //   n2 MFMA: accv[rt*2+wt] = D tile (raw dead by then)
    f32x4 accv[6];
#pragma unroll
    for (int i = 0; i < 6; ++i) accv[i] = (f32x4){0.f, 0.f, 0.f, 0.f};

    // ---- phase 1: A0 tile 48(r) x 32(w), K=256, coalesced frag loads ----
    f16x8 af[2][3], bf[2][2];
#pragma unroll
    for (int mt = 0; mt < 3; ++mt) af[0][mt] = *(const f16x8*)(aB + (mt * 8 + 0) * 512);
#pragma unroll
    for (int nt = 0; nt < 2; ++nt) bf[0][nt] = *(const f16x8*)(bB + (nt * 8 + 0) * 512);

#pragma unroll
    for (int ks = 0; ks < 8; ++ks) {
        const int cur = ks & 1, nxt = cur ^ 1;
        if (ks < 7) {
#pragma unroll
            for (int mt = 0; mt < 3; ++mt)
                af[nxt][mt] = *(const f16x8*)(aB + (mt * 8 + ks + 1) * 512);
#pragma unroll
            for (int nt = 0; nt < 2; ++nt)
                bf[nxt][nt] = *(const f16x8*)(bB + (nt * 8 + ks + 1) * 512);
        }
#pragma unroll
        for (int mt = 0; mt < 3; ++mt)
#pragma unroll
            for (int nt = 0; nt < 2; ++nt)
                accv[mt * 2 + nt] = __builtin_amdgcn_mfma_f32_16x16x32_f16(af[cur][mt], bf[cur][nt], accv[mt * 2 + nt], 0, 0, 0);
    }
    // lane holds raw[r][w]: r = mt*16 + kg*4 + v, w = nt*16 + lm

    // ---- norm over w -> coef[r] (log2e folded) per lane's 12 rows ----
    float coef[12];
#pragma unroll
    for (int mt = 0; mt < 3; ++mt)
#pragma unroll
        for (int v = 0; v < 4; ++v) {
            const int idx = mt * 4 + v;
            const float one_m = 1.f - mr[idx];
            float p = 0.f;
#pragma unroll
            for (int nt = 0; nt < 2; ++nt) {
                const float raw = accv[mt * 2 + nt][v];
                const float X = (raw >= 0.f ? raw : 0.1f * raw) + one_m;
                p += X * X;
            }
            p += __shfl_xor(p, 1);
            p += __shfl_xor(p, 2);
            p += __shfl_xor(p, 4);
            p += __shfl_xor(p, 8);
            coef[idx] = (LAMf * LOG2Ef) / (sqrtf(p) + EPSf);
        }

    // ---- E = exp2(X*coef)*m -> LDS [w][72] f16 only (no reg copy) ----
    _Float16* sEw = &sE[wv][0];
    float den[2] = {0.f, 0.f}, Wv[2] = {0.f, 0.f};
#pragma unroll
    for (int nt = 0; nt < 2; ++nt) {
        const int w = nt * 16 + lm;
#pragma unroll
        for (int mt = 0; mt < 3; ++mt) {
            f16x4 pk;
#pragma unroll
            for (int v = 0; v < 4; ++v) {
                const int idx = mt * 4 + v;
                const float raw = accv[mt * 2 + nt][v];
                const float X = (raw >= 0.f ? raw : 0.1f * raw) + (1.f - mr[idx]);
                const float E = exp2f(X * coef[idx]) * mr[idx];
                den[nt] += E;
                Wv[nt] += E * raw;
                pk[v] = (_Float16)E;
            }
            *(f16x4*)&sEw[w * 72 + mt * 16 + kg * 4] = pk;
        }
        // zero K-pad k = 48..63
        f16x4 z4; z4[0] = z4[1] = z4[2] = z4[3] = (_Float16)0.f;
        *(f16x4*)&sEw[w * 72 + 48 + kg * 4] = z4;
    }
    // reduce den/W over kg (rows split across kg)
#pragma unroll
    for (int nt = 0; nt < 2; ++nt) {
        den[nt] += __shfl_xor(den[nt], 16);
        den[nt] += __shfl_xor(den[nt], 32);
        Wv[nt]  += __shfl_xor(Wv[nt], 16);
        Wv[nt]  += __shfl_xor(Wv[nt], 32);
    }

    // ---- n2: D = G(48x48) * E(48x32) -> C-layout; raw dead, accv reused ----
#pragma unroll
    for (int i = 0; i < 6; ++i) accv[i] = (f32x4){0.f, 0.f, 0.f, 0.f};
#pragma unroll
    for (int ks = 0; ks < 2; ++ks) {
        f16x8 ef[2], gf[3];
#pragma unroll
        for (int wt = 0; wt < 2; ++wt)
            ef[wt] = *(const f16x8*)&sEw[(wt * 16 + lm) * 72 + ks * 32 + kg * 8];
#pragma unroll
        for (int rt = 0; rt < 3; ++rt)
            gf[rt] = *(const f16x8*)(gB + (rt * 2 + ks) * 512);
#pragma unroll
        for (int rt = 0; rt < 3; ++rt)
#pragma unroll
            for (int wt = 0; wt < 2; ++wt)
                accv[rt * 2 + wt] = __builtin_amdgcn_mfma_f32_16x16x32_f16(gf[rt], ef[wt], accv[rt * 2 + wt], 0, 0, 0);
    }
    // n2[w] = sum_r D[r][w]*E[r][w]: E read back from LDS (C-layout aligned)
    float n2v[2];
#pragma unroll
    for (int nt = 0; nt < 2; ++nt) {
        const int w = nt * 16 + lm;
        float p2 = 0.f;
#pragma unroll
        for (int rt = 0; rt < 3; ++rt) {
            f16x4 e4 = *(const f16x4*)&sEw[w * 72 + rt * 16 + kg * 4];
#pragma unroll
            for (int v = 0; v < 4; ++v)
                p2 += accv[rt * 2 + nt][v] * (float)e4[v];
        }
        p2 += __shfl_xor(p2, 16);
        p2 += __shfl_xor(p2, 32);
        n2v[nt] = p2;
    }

    // ---- final: cos (softmax denominators cancel), sum over words ----
    {
        float tot = 0.f;
#pragma unroll
        for (int nt = 0; nt < 2; ++nt) {
            const int w = nt * 16 + lm;
            const float n2 = fmaxf(n2v[nt], 0.f);
            const float cosv = Wv[nt] / fmaxf(n1v[nt] * sqrtf(n2), EPSf * den[nt]);
            tot += (w < sl) ? cosv : 0.f;
        }
        tot += __shfl_xor(tot, 1);
        tot += __shfl_xor(tot, 2);
        tot += __shfl_xor(tot, 4);
        tot += __shfl_xor(tot, 8);
        if (lane == 0) ws[WS_SCORES + b * NB + c] = tot / (float)sl;
    }
}

// ---------------- contrastive loss over 128x128 scores ----------------
__global__ __launch_bounds__(128) void loss_kernel(
    const float* __restrict__ scores, const int* __restrict__ qid,
    float* __restrict__ out)
{
    __shared__ int   s_q[NB];
    __shared__ float s_c[NB];
    __shared__ float s_v[NB];
    const int i = threadIdx.x;
    s_q[i] = qid[i];
    __syncthreads();

    const int q = s_q[i];
    bool dup = false;
    for (int j = 0; j < i; ++j) dup = dup || (s_q[j] == q);

    const float* row = scores + i * NB;
    float mx = -1e30f;
    for (int j = 0; j < NB; ++j) {
        float l = (row[j] - ((j == i) ? MARGINf : 0.f)) * TEMPf;
        mx = fmaxf(mx, l);
    }
    float sum = 0.f;
    for (int j = 0; j < NB; ++j) {
        float l = (row[j] - ((j == i) ? MARGINf : 0.f)) * TEMPf;
        sum += expf(l - mx);
    }
    const float logZ = mx + logf(sum);
    const float picked = (row[i] - MARGINf) * TEMPf;
    const float valid = dup ? 0.f : 1.f;
    s_c[i] = (logZ - picked) * valid;
    s_v[i] = valid;
    __syncthreads();
    if (i == 0) {
        float a = 0.f, v = 0.f;
        for (int j = 0; j < NB; ++j) { a += s_c[j]; v += s_v[j]; }
        out[0] = a / fmaxf(v, 1.f);
    }
}

extern "C" void kernel_launch(void* const* d_in, const int* in_sizes, int n_in,
                              void* d_out, int out_size, void* d_ws, size_t ws_size,
                              hipStream_t stream) {
    const float* im      = (const float*)d_in[0];
    const float* s       = (const float*)d_in[1];
    const int*   s_l     = (const int*)d_in[2];
    const float* im_mask = (const float*)d_in[3];
    const int*   qid     = (const int*)d_in[4];

    float* ws  = (float*)d_ws;
    float* out = (float*)d_out;

    prep4_kernel<<<NB, 256, 0, stream>>>(im, s, s_l, ws);
    wavefused5_kernel<<<dim3(32, NB), 256, 0, stream>>>(s_l, im_mask, ws);
    loss_kernel<<<1, 128, 0, stream>>>(ws + WS_SCORES, qid, out);
}

// Round 15
// 167.451 us; speedup vs baseline: 1.1688x; 1.1688x over previous
//
#include <hip/hip_runtime.h>
#include <hip/hip_bf16.h>
#include <math.h>

#define NB 128   // batch
#define NR 36    // regions
#define NW 32    // words
#define ND 256   // feature dim

#define MARGINf 0.05f
#define TEMPf   14.0f
#define LAMf    9.0f
#define EPSf    1e-8f
#define LOG2Ef  1.4426950408889634f

typedef _Float16 f16x8 __attribute__((ext_vector_type(8)));
typedef _Float16 f16x4 __attribute__((ext_vector_type(4)));
typedef float    f32x4 __attribute__((ext_vector_type(4)));

// ================= workspace layout (float offsets) =================
// All GEMM operands stored in MFMA-fragment order ("swizzled"):
//   fragment f, lane l, elem j  ->  base + f*512 + l*8 + j   (halves)
// so a wave's f16x8 fragment load = 64 lanes x 16B contiguous = 1KB burst.
#define WS_SCORES 0
#define WS_N1     16384
#define WS_GW     20480                   // f16[128][6*512]   (rt*2+ks frags)
#define GW_H      3072
#define WS_IMW    217088                  // f16[128][24*512]  (mt*8+ks frags)
#define IMW_H     12288
#define WS_SHW    1003520                 // f16[128][16*512]  (nt*8+ks frags)
#define SHW_H     8192

// =====================================================================
// prep4: build swizzled f16 operands (imw, shw word-masked, Gw) + n1
// =====================================================================
__global__ __launch_bounds__(256) void prep4_kernel(
    const float* __restrict__ im, const float* __restrict__ s,
    const int* __restrict__ s_l, float* __restrict__ ws)
{
    const int b = blockIdx.x;
    const int t = threadIdx.x;
    __shared__ float s_imf[NR * 260];
    __shared__ _Float16 s_G[48 * 72];

    const float4* im4 = (const float4*)(im + (size_t)b * NR * ND);
    for (int i = t; i < NR * 64; i += 256) {
        int r = i >> 6, c4 = i & 63;
        *(float4*)&s_imf[r * 260 + 4 * c4] = im4[i];
    }
    // zero G LDS (1728 u32)
    for (int i = t; i < 1728; i += 256) ((unsigned int*)s_G)[i] = 0u;
    __syncthreads();

    // Gram f16 into LDS [48][72], fill 36x36
    for (int i = t; i < NR * NR; i += 256) {
        int r = i / NR, rp = i - r * NR;
        const float4* a  = (const float4*)&s_imf[r * 260];
        const float4* bb = (const float4*)&s_imf[rp * 260];
        float acc = 0.f;
        for (int k = 0; k < 64; ++k) {
            float4 x = a[k], y = bb[k];
            acc += x.x * y.x + x.y * y.y + x.z * y.z + x.w * y.w;
        }
        s_G[r * 72 + rp] = (_Float16)acc;
    }
    __syncthreads();

    // Gw swizzled: 6 fragments (rt*2+ks) x 64 lanes
    _Float16* Gw = (_Float16*)(ws + WS_GW) + (size_t)b * GW_H;
    for (int i = t; i < 6 * 64; i += 256) {
        const int f = i >> 6, l = i & 63;
        const int rt = f >> 1, ks = f & 1;
        const int lm = l & 15, kg = l >> 4;
        f16x8 h = *(const f16x8*)&s_G[(rt * 16 + lm) * 72 + ks * 32 + kg * 8];
        *(f16x8*)((_Float16*)Gw + f * 512 + l * 8) = h;
    }

    // imw swizzled: 24 fragments (mt*8+ks) x 64 lanes, rows >=36 zero
    _Float16* imw = (_Float16*)(ws + WS_IMW) + (size_t)b * IMW_H;
    for (int i = t; i < 24 * 64; i += 256) {
        const int f = i >> 6, l = i & 63;
        const int mt = f >> 3, ks = f & 7;
        const int lm = l & 15, kg = l >> 4;
        const int r = mt * 16 + lm;
        f16x8 h;
        if (r < NR) {
            const int k0 = ks * 32 + kg * 8;
            const float4 a  = *(const float4*)&s_imf[r * 260 + k0];
            const float4 bb = *(const float4*)&s_imf[r * 260 + k0 + 4];
            h[0] = (_Float16)a.x;  h[1] = (_Float16)a.y;
            h[2] = (_Float16)a.z;  h[3] = (_Float16)a.w;
            h[4] = (_Float16)bb.x; h[5] = (_Float16)bb.y;
            h[6] = (_Float16)bb.z; h[7] = (_Float16)bb.w;
        } else {
#pragma unroll
            for (int k = 0; k < 8; ++k) h[k] = (_Float16)0.f;
        }
        *(f16x8*)(imw + f * 512 + l * 8) = h;
    }

    // shw swizzled: 16 fragments (nt*8+ks) x 64 lanes, word-masked
    const int sl = s_l[b];
    _Float16* shw = (_Float16*)(ws + WS_SHW) + (size_t)b * SHW_H;
    const float4* s4 = (const float4*)(s + (size_t)b * NW * ND);
    for (int i = t; i < 16 * 64; i += 256) {
        const int f = i >> 6, l = i & 63;
        const int nt = f >> 3, ks = f & 7;
        const int lm = l & 15, kg = l >> 4;
        const int w = nt * 16 + lm;
        f16x8 h;
        if (w < sl) {
            const int k0 = ks * 32 + kg * 8;     // multiple of 8 floats
            const float4 a  = s4[w * 64 + (k0 >> 2)];
            const float4 bb = s4[w * 64 + (k0 >> 2) + 1];
            h[0] = (_Float16)a.x;  h[1] = (_Float16)a.y;
            h[2] = (_Float16)a.z;  h[3] = (_Float16)a.w;
            h[4] = (_Float16)bb.x; h[5] = (_Float16)bb.y;
            h[6] = (_Float16)bb.z; h[7] = (_Float16)bb.w;
        } else {
#pragma unroll
            for (int k = 0; k < 8; ++k) h[k] = (_Float16)0.f;
        }
        *(f16x8*)(shw + f * 512 + l * 8) = h;
    }

    // n1[b][w]
    {
        const int w = t >> 3, g = t & 7;
        float acc = 0.f;
        for (int j = 0; j < 8; ++j) {
            float4 v = s4[w * 64 + g * 8 + j];
            acc += v.x * v.x + v.y * v.y + v.z * v.z + v.w * v.w;
        }
        acc += __shfl_down(acc, 4, 8);
        acc += __shfl_down(acc, 2, 8);
        acc += __shfl_down(acc, 1, 8);
        if (g == 0) ws[WS_N1 + b * NW + w] = sqrtf(acc);
    }
}

// =====================================================================
// wavefused6: ONE WAVE per (image b, caption c), ZERO barriers.
// R13 structure (er[] kept, bounds (256,5) -- no spill) with
// single-buffered phase-1 fragments to shrink peak register live set.
// grid (32, 128), block 256 = 4 independent waves. LDS ~18.5 KB.
// =====================================================================
__global__ __launch_bounds__(256, 5) void wavefused6_kernel(
    const int* __restrict__ s_l, const float* __restrict__ im_mask,
    float* __restrict__ ws)
{
    const int t = threadIdx.x;
    const int wv = t >> 6, lane = t & 63;
    const int lm = lane & 15, kg = lane >> 4;
    const int b = blockIdx.y;
    const int c = blockIdx.x * 4 + wv;

    __shared__ _Float16 sE[4][32 * 72];   // per-wave E tile [w][k], 4.6 KB each

    const _Float16* aB = (const _Float16*)(ws + WS_IMW) + (size_t)b * IMW_H + lane * 8;
    const _Float16* bB = (const _Float16*)(ws + WS_SHW) + (size_t)c * SHW_H + lane * 8;
    const _Float16* gB = (const _Float16*)(ws + WS_GW) + (size_t)b * GW_H + lane * 8;

    // early small loads (L1/L2-resident, broadcast-friendly)
    float n1v[2];
#pragma unroll
    for (int nt = 0; nt < 2; ++nt)
        n1v[nt] = ws[WS_N1 + c * NW + nt * 16 + lm];
    float mr[12];
#pragma unroll
    for (int mt = 0; mt < 3; ++mt)
#pragma unroll
        for (int v = 0; v < 4; ++v) {
            const int r = mt * 16 + kg * 4 + v;
            mr[mt * 4 + v] = (r < NR) ? im_mask[b * NR + r] : 0.f;
        }
    const int sl = s_l[c];

    // accumulator array, aliased:
    //   phase 1: accv[mt*2+nt] = A0 raw tile
    //   n2 MFMA: accv[rt*2+wt] = D tile (raw dead by then)
    f32x4 accv[6];
#pragma unroll
    for (int i = 0; i < 6; ++i) accv[i] = (f32x4){0.f, 0.f, 0.f, 0.f};

    // ---- phase 1: A0 tile 48(r) x 32(w), K=256, single-buffered frags ----
    // (compiler schedules loads ahead via its own vmcnt pipelining; keeping
    //  the live set small lets the HW fit more waves -> TLP latency hiding)
#pragma unroll
    for (int ks = 0; ks < 8; ++ks) {
        f16x8 af[3], bf[2];
#pragma unroll
        for (int mt = 0; mt < 3; ++mt)
            af[mt] = *(const f16x8*)(aB + (mt * 8 + ks) * 512);
#pragma unroll
        for (int nt = 0; nt < 2; ++nt)
            bf[nt] = *(const f16x8*)(bB + (nt * 8 + ks) * 512);
#pragma unroll
        for (int mt = 0; mt < 3; ++mt)
#pragma unroll
            for (int nt = 0; nt < 2; ++nt)
                accv[mt * 2 + nt] = __builtin_amdgcn_mfma_f32_16x16x32_f16(af[mt], bf[nt], accv[mt * 2 + nt], 0, 0, 0);
    }
    // lane holds raw[r][w]: r = mt*16 + kg*4 + v, w = nt*16 + lm

    // ---- norm over w -> coef[r] (log2e folded) per lane's 12 rows ----
    float coef[12];
#pragma unroll
    for (int mt = 0; mt < 3; ++mt)
#pragma unroll
        for (int v = 0; v < 4; ++v) {
            const int idx = mt * 4 + v;
            const float one_m = 1.f - mr[idx];
            float p = 0.f;
#pragma unroll
            for (int nt = 0; nt < 2; ++nt) {
                const float raw = accv[mt * 2 + nt][v];
                const float X = (raw >= 0.f ? raw : 0.1f * raw) + one_m;
                p += X * X;
            }
            p += __shfl_xor(p, 1);
            p += __shfl_xor(p, 2);
            p += __shfl_xor(p, 4);
            p += __shfl_xor(p, 8);
            coef[idx] = (LAMf * LOG2Ef) / (sqrtf(p) + EPSf);
        }

    // ---- E = exp2(X*coef)*m; keep E in f32 regs AND LDS [w][72] f16 ----
    _Float16* sEw = &sE[wv][0];
    f32x4 er[6];
    float den[2] = {0.f, 0.f}, Wv[2] = {0.f, 0.f};
#pragma unroll
    for (int nt = 0; nt < 2; ++nt) {
        const int w = nt * 16 + lm;
#pragma unroll
        for (int mt = 0; mt < 3; ++mt) {
            f16x4 pk;
#pragma unroll
            for (int v = 0; v < 4; ++v) {
                const int idx = mt * 4 + v;
                const float raw = accv[mt * 2 + nt][v];
                const float X = (raw >= 0.f ? raw : 0.1f * raw) + (1.f - mr[idx]);
                const float E = exp2f(X * coef[idx]) * mr[idx];
                er[mt * 2 + nt][v] = E;
                den[nt] += E;
                Wv[nt] += E * raw;
                pk[v] = (_Float16)E;
            }
            *(f16x4*)&sEw[w * 72 + mt * 16 + kg * 4] = pk;
        }
        // zero K-pad k = 48..63
        f16x4 z4; z4[0] = z4[1] = z4[2] = z4[3] = (_Float16)0.f;
        *(f16x4*)&sEw[w * 72 + 48 + kg * 4] = z4;
    }
    // reduce den/W over kg (rows split across kg)
#pragma unroll
    for (int nt = 0; nt < 2; ++nt) {
        den[nt] += __shfl_xor(den[nt], 16);
        den[nt] += __shfl_xor(den[nt], 32);
        Wv[nt]  += __shfl_xor(Wv[nt], 16);
        Wv[nt]  += __shfl_xor(Wv[nt], 32);
    }

    // ---- n2: D = G(48x48) * E(48x32) -> C-layout aligned with er ----
    // accv reused as D (raw fully consumed above)
#pragma unroll
    for (int i = 0; i < 6; ++i) accv[i] = (f32x4){0.f, 0.f, 0.f, 0.f};
#pragma unroll
    for (int ks = 0; ks < 2; ++ks) {
        f16x8 ef[2], gf[3];
#pragma unroll
        for (int wt = 0; wt < 2; ++wt)
            ef[wt] = *(const f16x8*)&sEw[(wt * 16 + lm) * 72 + ks * 32 + kg * 8];
#pragma unroll
        for (int rt = 0; rt < 3; ++rt)
            gf[rt] = *(const f16x8*)(gB + (rt * 2 + ks) * 512);
#pragma unroll
        for (int rt = 0; rt < 3; ++rt)
#pragma unroll
            for (int wt = 0; wt < 2; ++wt)
                accv[rt * 2 + wt] = __builtin_amdgcn_mfma_f32_16x16x32_f16(gf[rt], ef[wt], accv[rt * 2 + wt], 0, 0, 0);
    }
    // n2[w] = sum_r D[r][w]*E[r][w]: pure register dot + kg reduction
    float n2v[2];
#pragma unroll
    for (int nt = 0; nt < 2; ++nt) {
        float p2 = 0.f;
#pragma unroll
        for (int rt = 0; rt < 3; ++rt)
#pragma unroll
            for (int v = 0; v < 4; ++v)
                p2 += accv[rt * 2 + nt][v] * er[rt * 2 + nt][v];
        p2 += __shfl_xor(p2, 16);
        p2 += __shfl_xor(p2, 32);
        n2v[nt] = p2;
    }

    // ---- final: cos (softmax denominators cancel), sum over words ----
    {
        float tot = 0.f;
#pragma unroll
        for (int nt = 0; nt < 2; ++nt) {
            const int w = nt * 16 + lm;
            const float n2 = fmaxf(n2v[nt], 0.f);
            const float cosv = Wv[nt] / fmaxf(n1v[nt] * sqrtf(n2), EPSf * den[nt]);
            tot += (w < sl) ? cosv : 0.f;
        }
        tot += __shfl_xor(tot, 1);
        tot += __shfl_xor(tot, 2);
        tot += __shfl_xor(tot, 4);
        tot += __shfl_xor(tot, 8);
        if (lane == 0) ws[WS_SCORES + b * NB + c] = tot / (float)sl;
    }
}

// ---------------- contrastive loss over 128x128 scores ----------------
__global__ __launch_bounds__(128) void loss_kernel(
    const float* __restrict__ scores, const int* __restrict__ qid,
    float* __restrict__ out)
{
    __shared__ int   s_q[NB];
    __shared__ float s_c[NB];
    __shared__ float s_v[NB];
    const int i = threadIdx.x;
    s_q[i] = qid[i];
    __syncthreads();

    const int q = s_q[i];
    bool dup = false;
    for (int j = 0; j < i; ++j) dup = dup || (s_q[j] == q);

    const float* row = scores + i * NB;
    float mx = -1e30f;
    for (int j = 0; j < NB; ++j) {
        float l = (row[j] - ((j == i) ? MARGINf : 0.f)) * TEMPf;
        mx = fmaxf(mx, l);
    }
    float sum = 0.f;
    for (int j = 0; j < NB; ++j) {
        float l = (row[j] - ((j == i) ? MARGINf : 0.f)) * TEMPf;
        sum += expf(l - mx);
    }
    const float logZ = mx + logf(sum);
    const float picked = (row[i] - MARGINf) * TEMPf;
    const float valid = dup ? 0.f : 1.f;
    s_c[i] = (logZ - picked) * valid;
    s_v[i] = valid;
    __syncthreads();
    if (i == 0) {
        float a = 0.f, v = 0.f;
        for (int j = 0; j < NB; ++j) { a += s_c[j]; v += s_v[j]; }
        out[0] = a / fmaxf(v, 1.f);
    }
}

extern "C" void kernel_launch(void* const* d_in, const int* in_sizes, int n_in,
                              void* d_out, int out_size, void* d_ws, size_t ws_size,
                              hipStream_t stream) {
    const float* im      = (const float*)d_in[0];
    const float* s       = (const float*)d_in[1];
    const int*   s_l     = (const int*)d_in[2];
    const float* im_mask = (const float*)d_in[3];
    const int*   qid     = (const int*)d_in[4];

    float* ws  = (float*)d_ws;
    float* out = (float*)d_out;

    prep4_kernel<<<NB, 256, 0, stream>>>(im, s, s_l, ws);
    wavefused6_kernel<<<dim3(32, NB), 256, 0, stream>>>(s_l, im_mask, ws);
    loss_kernel<<<1, 128, 0, stream>>>(ws + WS_SCORES, qid, out);
}

// Round 16
// 159.454 us; speedup vs baseline: 1.2274x; 1.0502x over previous
//
#include <hip/hip_runtime.h>
#include <hip/hip_bf16.h>
#include <math.h>

#define NB 128   // batch
#define NR 36    // regions
#define NW 32    // words
#define ND 256   // feature dim

#define MARGINf 0.05f
#define TEMPf   14.0f
#define LAMf    9.0f
#define EPSf    1e-8f
#define LOG2Ef  1.4426950408889634f

typedef _Float16 f16x8 __attribute__((ext_vector_type(8)));
typedef _Float16 f16x4 __attribute__((ext_vector_type(4)));
typedef float    f32x4 __attribute__((ext_vector_type(4)));

// ================= workspace layout (float offsets) =================
// All GEMM operands stored in MFMA-fragment order ("swizzled"):
//   fragment f, lane l, elem j  ->  base + f*512 + l*8 + j   (halves)
// so a wave's f16x8 fragment load = 64 lanes x 16B contiguous = 1KB burst.
#define WS_SCORES 0
#define WS_N1     16384
#define WS_GW     20480                   // f16[128][6*512]   (rt*2+ks frags)
#define GW_H      3072
#define WS_IMW    217088                  // f16[128][24*512]  (mt*8+ks frags)
#define IMW_H     12288
#define WS_SHW    1003520                 // f16[128][16*512]  (nt*8+ks frags)
#define SHW_H     8192

// =====================================================================
// prep4: build swizzled f16 operands (imw, shw word-masked, Gw) + n1
// =====================================================================
__global__ __launch_bounds__(256) void prep4_kernel(
    const float* __restrict__ im, const float* __restrict__ s,
    const int* __restrict__ s_l, float* __restrict__ ws)
{
    const int b = blockIdx.x;
    const int t = threadIdx.x;
    __shared__ float s_imf[NR * 260];
    __shared__ _Float16 s_G[48 * 72];

    const float4* im4 = (const float4*)(im + (size_t)b * NR * ND);
    for (int i = t; i < NR * 64; i += 256) {
        int r = i >> 6, c4 = i & 63;
        *(float4*)&s_imf[r * 260 + 4 * c4] = im4[i];
    }
    // zero G LDS (1728 u32)
    for (int i = t; i < 1728; i += 256) ((unsigned int*)s_G)[i] = 0u;
    __syncthreads();

    // Gram f16 into LDS [48][72], fill 36x36
    for (int i = t; i < NR * NR; i += 256) {
        int r = i / NR, rp = i - r * NR;
        const float4* a  = (const float4*)&s_imf[r * 260];
        const float4* bb = (const float4*)&s_imf[rp * 260];
        float acc = 0.f;
        for (int k = 0; k < 64; ++k) {
            float4 x = a[k], y = bb[k];
            acc += x.x * y.x + x.y * y.y + x.z * y.z + x.w * y.w;
        }
        s_G[r * 72 + rp] = (_Float16)acc;
    }
    __syncthreads();

    // Gw swizzled: 6 fragments (rt*2+ks) x 64 lanes
    _Float16* Gw = (_Float16*)(ws + WS_GW) + (size_t)b * GW_H;
    for (int i = t; i < 6 * 64; i += 256) {
        const int f = i >> 6, l = i & 63;
        const int rt = f >> 1, ks = f & 1;
        const int lm = l & 15, kg = l >> 4;
        f16x8 h = *(const f16x8*)&s_G[(rt * 16 + lm) * 72 + ks * 32 + kg * 8];
        *(f16x8*)((_Float16*)Gw + f * 512 + l * 8) = h;
    }

    // imw swizzled: 24 fragments (mt*8+ks) x 64 lanes, rows >=36 zero
    _Float16* imw = (_Float16*)(ws + WS_IMW) + (size_t)b * IMW_H;
    for (int i = t; i < 24 * 64; i += 256) {
        const int f = i >> 6, l = i & 63;
        const int mt = f >> 3, ks = f & 7;
        const int lm = l & 15, kg = l >> 4;
        const int r = mt * 16 + lm;
        f16x8 h;
        if (r < NR) {
            const int k0 = ks * 32 + kg * 8;
            const float4 a  = *(const float4*)&s_imf[r * 260 + k0];
            const float4 bb = *(const float4*)&s_imf[r * 260 + k0 + 4];
            h[0] = (_Float16)a.x;  h[1] = (_Float16)a.y;
            h[2] = (_Float16)a.z;  h[3] = (_Float16)a.w;
            h[4] = (_Float16)bb.x; h[5] = (_Float16)bb.y;
            h[6] = (_Float16)bb.z; h[7] = (_Float16)bb.w;
        } else {
#pragma unroll
            for (int k = 0; k < 8; ++k) h[k] = (_Float16)0.f;
        }
        *(f16x8*)(imw + f * 512 + l * 8) = h;
    }

    // shw swizzled: 16 fragments (nt*8+ks) x 64 lanes, word-masked
    const int sl = s_l[b];
    _Float16* shw = (_Float16*)(ws + WS_SHW) + (size_t)b * SHW_H;
    const float4* s4 = (const float4*)(s + (size_t)b * NW * ND);
    for (int i = t; i < 16 * 64; i += 256) {
        const int f = i >> 6, l = i & 63;
        const int nt = f >> 3, ks = f & 7;
        const int lm = l & 15, kg = l >> 4;
        const int w = nt * 16 + lm;
        f16x8 h;
        if (w < sl) {
            const int k0 = ks * 32 + kg * 8;     // multiple of 8 floats
            const float4 a  = s4[w * 64 + (k0 >> 2)];
            const float4 bb = s4[w * 64 + (k0 >> 2) + 1];
            h[0] = (_Float16)a.x;  h[1] = (_Float16)a.y;
            h[2] = (_Float16)a.z;  h[3] = (_Float16)a.w;
            h[4] = (_Float16)bb.x; h[5] = (_Float16)bb.y;
            h[6] = (_Float16)bb.z; h[7] = (_Float16)bb.w;
        } else {
#pragma unroll
            for (int k = 0; k < 8; ++k) h[k] = (_Float16)0.f;
        }
        *(f16x8*)(shw + f * 512 + l * 8) = h;
    }

    // n1[b][w]
    {
        const int w = t >> 3, g = t & 7;
        float acc = 0.f;
        for (int j = 0; j < 8; ++j) {
            float4 v = s4[w * 64 + g * 8 + j];
            acc += v.x * v.x + v.y * v.y + v.z * v.z + v.w * v.w;
        }
        acc += __shfl_down(acc, 4, 8);
        acc += __shfl_down(acc, 2, 8);
        acc += __shfl_down(acc, 1, 8);
        if (g == 0) ws[WS_N1 + b * NW + w] = sqrtf(acc);
    }
}

// =====================================================================
// wavefused4 (R13 best): ONE WAVE per (image b, caption c), ZERO barriers.
// Explicit 2-deep fragment double-buffer + er[] register E + (256,5).
// n2 via D = G*E in C-layout (register dot with E, no extract shuffles).
// grid (32, 128), block 256 = 4 independent waves. LDS ~18.5 KB.
// =====================================================================
__global__ __launch_bounds__(256, 5) void wavefused4_kernel(
    const int* __restrict__ s_l, const float* __restrict__ im_mask,
    float* __restrict__ ws)
{
    const int t = threadIdx.x;
    const int wv = t >> 6, lane = t & 63;
    const int lm = lane & 15, kg = lane >> 4;
    const int b = blockIdx.y;
    const int c = blockIdx.x * 4 + wv;

    __shared__ _Float16 sE[4][32 * 72];   // per-wave E tile [w][k], 4.6 KB each

    const _Float16* aB = (const _Float16*)(ws + WS_IMW) + (size_t)b * IMW_H + lane * 8;
    const _Float16* bB = (const _Float16*)(ws + WS_SHW) + (size_t)c * SHW_H + lane * 8;
    const _Float16* gB = (const _Float16*)(ws + WS_GW) + (size_t)b * GW_H + lane * 8;

    // early small loads (L1/L2-resident, broadcast-friendly)
    float n1v[2];
#pragma unroll
    for (int nt = 0; nt < 2; ++nt)
        n1v[nt] = ws[WS_N1 + c * NW + nt * 16 + lm];
    float mr[12];
#pragma unroll
    for (int mt = 0; mt < 3; ++mt)
#pragma unroll
        for (int v = 0; v < 4; ++v) {
            const int r = mt * 16 + kg * 4 + v;
            mr[mt * 4 + v] = (r < NR) ? im_mask[b * NR + r] : 0.f;
        }
    const int sl = s_l[c];

    // accumulator array, aliased:
    //   phase 1: accv[mt*2+nt] = A0 raw tile
    //   n2 MFMA: accv[rt*2+wt] = D tile (raw dead by then)
    f32x4 accv[6];
#pragma unroll
    for (int i = 0; i < 6; ++i) accv[i] = (f32x4){0.f, 0.f, 0.f, 0.f};

    // ---- phase 1: A0 tile 48(r) x 32(w), K=256, coalesced frag loads ----
    f16x8 af[2][3], bf[2][2];
#pragma unroll
    for (int mt = 0; mt < 3; ++mt) af[0][mt] = *(const f16x8*)(aB + (mt * 8 + 0) * 512);
#pragma unroll
    for (int nt = 0; nt < 2; ++nt) bf[0][nt] = *(const f16x8*)(bB + (nt * 8 + 0) * 512);

#pragma unroll
    for (int ks = 0; ks < 8; ++ks) {
        const int cur = ks & 1, nxt = cur ^ 1;
        if (ks < 7) {
#pragma unroll
            for (int mt = 0; mt < 3; ++mt)
                af[nxt][mt] = *(const f16x8*)(aB + (mt * 8 + ks + 1) * 512);
#pragma unroll
            for (int nt = 0; nt < 2; ++nt)
                bf[nxt][nt] = *(const f16x8*)(bB + (nt * 8 + ks + 1) * 512);
        }
#pragma unroll
        for (int mt = 0; mt < 3; ++mt)
#pragma unroll
            for (int nt = 0; nt < 2; ++nt)
                accv[mt * 2 + nt] = __builtin_amdgcn_mfma_f32_16x16x32_f16(af[cur][mt], bf[cur][nt], accv[mt * 2 + nt], 0, 0, 0);
    }
    // lane holds raw[r][w]: r = mt*16 + kg*4 + v, w = nt*16 + lm

    // ---- norm over w -> coef[r] (log2e folded) per lane's 12 rows ----
    float coef[12];
#pragma unroll
    for (int mt = 0; mt < 3; ++mt)
#pragma unroll
        for (int v = 0; v < 4; ++v) {
            const int idx = mt * 4 + v;
            const float one_m = 1.f - mr[idx];
            float p = 0.f;
#pragma unroll
            for (int nt = 0; nt < 2; ++nt) {
                const float raw = accv[mt * 2 + nt][v];
                const float X = (raw >= 0.f ? raw : 0.1f * raw) + one_m;
                p += X * X;
            }
            p += __shfl_xor(p, 1);
            p += __shfl_xor(p, 2);
            p += __shfl_xor(p, 4);
            p += __shfl_xor(p, 8);
            coef[idx] = (LAMf * LOG2Ef) / (sqrtf(p) + EPSf);
        }

    // ---- E = exp2(X*coef)*m; keep E in f32 regs AND LDS [w][72] f16 ----
    _Float16* sEw = &sE[wv][0];
    f32x4 er[6];
    float den[2] = {0.f, 0.f}, Wv[2] = {0.f, 0.f};
#pragma unroll
    for (int nt = 0; nt < 2; ++nt) {
        const int w = nt * 16 + lm;
#pragma unroll
        for (int mt = 0; mt < 3; ++mt) {
            f16x4 pk;
#pragma unroll
            for (int v = 0; v < 4; ++v) {
                const int idx = mt * 4 + v;
                const float raw = accv[mt * 2 + nt][v];
                const float X = (raw >= 0.f ? raw : 0.1f * raw) + (1.f - mr[idx]);
                const float E = exp2f(X * coef[idx]) * mr[idx];
                er[mt * 2 + nt][v] = E;
                den[nt] += E;
                Wv[nt] += E * raw;
                pk[v] = (_Float16)E;
            }
            *(f16x4*)&sEw[w * 72 + mt * 16 + kg * 4] = pk;
        }
        // zero K-pad k = 48..63 (G kills it numerically, but avoid stray NaN bits)
        f16x4 z4; z4[0] = z4[1] = z4[2] = z4[3] = (_Float16)0.f;
        *(f16x4*)&sEw[w * 72 + 48 + kg * 4] = z4;
    }
    // reduce den/W over kg (rows split across kg)
#pragma unroll
    for (int nt = 0; nt < 2; ++nt) {
        den[nt] += __shfl_xor(den[nt], 16);
        den[nt] += __shfl_xor(den[nt], 32);
        Wv[nt]  += __shfl_xor(Wv[nt], 16);
        Wv[nt]  += __shfl_xor(Wv[nt], 32);
    }

    // ---- n2: D = G(48x48) * E(48x32) -> C-layout aligned with er ----
    // accv reused as D (raw fully consumed above)
#pragma unroll
    for (int i = 0; i < 6; ++i) accv[i] = (f32x4){0.f, 0.f, 0.f, 0.f};
#pragma unroll
    for (int ks = 0; ks < 2; ++ks) {
        f16x8 ef[2], gf[3];
#pragma unroll
        for (int wt = 0; wt < 2; ++wt)
            ef[wt] = *(const f16x8*)&sEw[(wt * 16 + lm) * 72 + ks * 32 + kg * 8];
#pragma unroll
        for (int rt = 0; rt < 3; ++rt)
            gf[rt] = *(const f16x8*)(gB + (rt * 2 + ks) * 512);
#pragma unroll
        for (int rt = 0; rt < 3; ++rt)
#pragma unroll
            for (int wt = 0; wt < 2; ++wt)
                accv[rt * 2 + wt] = __builtin_amdgcn_mfma_f32_16x16x32_f16(gf[rt], ef[wt], accv[rt * 2 + wt], 0, 0, 0);
    }
    // n2[w] = sum_r D[r][w]*E[r][w]: pure register dot + kg reduction
    float n2v[2];
#pragma unroll
    for (int nt = 0; nt < 2; ++nt) {
        float p2 = 0.f;
#pragma unroll
        for (int rt = 0; rt < 3; ++rt)
#pragma unroll
            for (int v = 0; v < 4; ++v)
                p2 += accv[rt * 2 + nt][v] * er[rt * 2 + nt][v];
        p2 += __shfl_xor(p2, 16);
        p2 += __shfl_xor(p2, 32);
        n2v[nt] = p2;
    }

    // ---- final: cos (softmax denominators cancel), sum over words ----
    {
        float tot = 0.f;
#pragma unroll
        for (int nt = 0; nt < 2; ++nt) {
            const int w = nt * 16 + lm;
            const float n2 = fmaxf(n2v[nt], 0.f);
            const float cosv = Wv[nt] / fmaxf(n1v[nt] * sqrtf(n2), EPSf * den[nt]);
            tot += (w < sl) ? cosv : 0.f;
        }
        tot += __shfl_xor(tot, 1);
        tot += __shfl_xor(tot, 2);
        tot += __shfl_xor(tot, 4);
        tot += __shfl_xor(tot, 8);
        if (lane == 0) ws[WS_SCORES + b * NB + c] = tot / (float)sl;
    }
}

// ---------------- contrastive loss over 128x128 scores ----------------
__global__ __launch_bounds__(128) void loss_kernel(
    const float* __restrict__ scores, const int* __restrict__ qid,
    float* __restrict__ out)
{
    __shared__ int   s_q[NB];
    __shared__ float s_c[NB];
    __shared__ float s_v[NB];
    const int i = threadIdx.x;
    s_q[i] = qid[i];
    __syncthreads();

    const int q = s_q[i];
    bool dup = false;
    for (int j = 0; j < i; ++j) dup = dup || (s_q[j] == q);

    const float* row = scores + i * NB;
    float mx = -1e30f;
    for (int j = 0; j < NB; ++j) {
        float l = (row[j] - ((j == i) ? MARGINf : 0.f)) * TEMPf;
        mx = fmaxf(mx, l);
    }
    float sum = 0.f;
    for (int j = 0; j < NB; ++j) {
        float l = (row[j] - ((j == i) ? MARGINf : 0.f)) * TEMPf;
        sum += expf(l - mx);
    }
    const float logZ = mx + logf(sum);
    const float picked = (row[i] - MARGINf) * TEMPf;
    const float valid = dup ? 0.f : 1.f;
    s_c[i] = (logZ - picked) * valid;
    s_v[i] = valid;
    __syncthreads();
    if (i == 0) {
        float a = 0.f, v = 0.f;
        for (int j = 0; j < NB; ++j) { a += s_c[j]; v += s_v[j]; }
        out[0] = a / fmaxf(v, 1.f);
    }
}

extern "C" void kernel_launch(void* const* d_in, const int* in_sizes, int n_in,
                              void* d_out, int out_size, void* d_ws, size_t ws_size,
                              hipStream_t stream) {
    const float* im      = (const float*)d_in[0];
    const float* s       = (const float*)d_in[1];
    const int*   s_l     = (const int*)d_in[2];
    const float* im_mask = (const float*)d_in[3];
    const int*   qid     = (const int*)d_in[4];

    float* ws  = (float*)d_ws;
    float* out = (float*)d_out;

    prep4_kernel<<<NB, 256, 0, stream>>>(im, s, s_l, ws);
    wavefused4_kernel<<<dim3(32, NB), 256, 0, stream>>>(s_l, im_mask, ws);
    loss_kernel<<<1, 128, 0, stream>>>(ws + WS_SCORES, qid, out);
}